// Round 7
// baseline (126.026 us; speedup 1.0000x reference)
//
#include <hip/hip_runtime.h>

// Segment attention pooling, MI355X (gfx950).
// convw_pack (fp32 W -> bf16, MFMA-fragment order) ; segscan ;
// score_gemm (persistent 2-tile blocks, K-chunk ping-pong LDS, issue-early/
// write-late A staging, raw barriers, packed-B depth-1 prefetch) ; pool.

#define SEP_ID 102
#define Bn 64
#define Sn 512
#define Hn 768
#define Mn 21
#define BS (Bn * Sn)

typedef __attribute__((ext_vector_type(8))) short bf16x8;
typedef __attribute__((ext_vector_type(8))) unsigned short u16x8;
typedef __attribute__((ext_vector_type(4))) float f32x4;

__device__ inline unsigned short f2bf(float x) {
  unsigned int u = __builtin_bit_cast(unsigned int, x);
  u += 0x7fffu + ((u >> 16) & 1u);   // RNE
  return (unsigned short)(u >> 16);
}

__device__ inline u16x8 cvt8(float4 a, float4 b) {
  u16x8 r;
  r[0] = f2bf(a.x); r[1] = f2bf(a.y); r[2] = f2bf(a.z); r[3] = f2bf(a.w);
  r[4] = f2bf(b.x); r[5] = f2bf(b.y); r[6] = f2bf(b.z); r[7] = f2bf(b.w);
  return r;
}

__device__ inline float tanh_fast(float x) {
  float e = __builtin_amdgcn_exp2f(x * 2.885390081777927f); // 2*log2(e)
  return 1.f - 2.f * __builtin_amdgcn_rcpf(e + 1.f);
}

// ---------------- kernel 1: W fp32 -> bf16, packed in MFMA B-fragment order.
// chunk c = (ntile*24 + kstep)*64 + lane; holds W[ntile*16 + (lane&15)]
// [kstep*32 + (lane>>4)*8 ..+8]  -> score_gemm B loads are lane-contiguous.
__global__ void convw_kernel(const float* __restrict__ W, unsigned short* __restrict__ WBp) {
  int c = blockIdx.x * 256 + threadIdx.x;   // 73728 chunks, grid 288
  int nt = c / 1536;
  int r  = c % 1536;
  int ks = r >> 6;
  int ln = r & 63;
  int col = nt * 16 + (ln & 15);
  int k0  = ks * 32 + (ln >> 4) * 8;
  const float* src = &W[col * Hn + k0];
  float4 a = *reinterpret_cast<const float4*>(src);
  float4 b = *reinterpret_cast<const float4*>(src + 4);
  *reinterpret_cast<u16x8*>(&WBp[(size_t)c * 8]) = cvt8(a, b);
}

// ---------------- kernel 2: per-batch segment scan
__global__ void segscan_kernel(const int* __restrict__ ids,
                               unsigned char* __restrict__ segv,
                               int* __restrict__ nsep) {
  int b = blockIdx.x;
  int s = threadIdx.x;
  __shared__ int cs[Sn];
  int sep = (ids[b * Sn + s] == SEP_ID) ? 1 : 0;
  cs[s] = sep;
  __syncthreads();
  for (int off = 1; off < Sn; off <<= 1) {
    int add = (s >= off) ? cs[s - off] : 0;
    __syncthreads();
    cs[s] += add;
    __syncthreads();
  }
  int csum = cs[s];
  int nb = cs[Sn - 1];
  int seg = csum - sep;
  bool valid = (!sep) && (s >= 1) && (seg < nb) && (seg < Mn);
  segv[b * Sn + s] = valid ? (unsigned char)seg : (unsigned char)0xFF;
  if (s == 0) nsep[b] = nb;
}

// ---------------- kernel 3 epilogue helper: tanh(pre+b)*v, reduce, store
__device__ inline void score_epilogue(f32x4 (&acc)[4][3],
                                      const float* __restrict__ bbias,
                                      const float* __restrict__ vvec,
                                      float* __restrict__ scores,
                                      float (*scpart)[64],
                                      size_t rowBase, int wid, int l15, int l4,
                                      int colBase, int t) {
  float sc[4][4];
#pragma unroll
  for (int mi = 0; mi < 4; ++mi)
#pragma unroll
    for (int r = 0; r < 4; ++r) sc[mi][r] = 0.f;
#pragma unroll
  for (int ni = 0; ni < 3; ++ni) {
    int col = colBase + ni * 16 + l15;
    float vv = vvec[col];
    float bb = bbias[col];
#pragma unroll
    for (int mi = 0; mi < 4; ++mi)
#pragma unroll
      for (int r = 0; r < 4; ++r)
        sc[mi][r] += tanh_fast(acc[mi][ni][r] + bb) * vv;
  }
#pragma unroll
  for (int off = 1; off < 16; off <<= 1)
#pragma unroll
    for (int mi = 0; mi < 4; ++mi)
#pragma unroll
      for (int r = 0; r < 4; ++r)
        sc[mi][r] += __shfl_xor(sc[mi][r], off, 64);
  if (l15 == 0) {
#pragma unroll
    for (int mi = 0; mi < 4; ++mi)
#pragma unroll
      for (int r = 0; r < 4; ++r)
        scpart[wid][mi * 16 + l4 * 4 + r] = sc[mi][r];
  }
  __syncthreads();
  if (t < 64) {
    float s = 0.f;
#pragma unroll
    for (int w = 0; w < 16; ++w) s += scpart[w][t];
    scores[rowBase + t] = s;
  }
}

// ---------------- kernel 3: scores = v . tanh(hidden @ W^T + b)
// Grid 256, persistent over 2 row-tiles of 64. 1024 thr = 16 waves,
// wave = 64 rows x 48 cols (acc 4x3 f32x4 = 48 regs).
// A staged per K-chunk of 256 (8 k-steps) into ping-pong LDS (2x32KB):
// issue loads at chunk start (regs), convert+ds_write after the MFMAs,
// raw s_barrier + lgkmcnt(0) only. B from packed WBp, depth-1 prefetch.
__global__ __launch_bounds__(1024, 4) void score_gemm_kernel(
    const float* __restrict__ hid, const unsigned short* __restrict__ WBp,
    const float* __restrict__ bbias, const float* __restrict__ vvec,
    float* __restrict__ scores) {
  __shared__ __align__(16) unsigned short As[2][64 * 256];  // 2 x 32 KB
  __shared__ float scpart[16][64];

  const int t = threadIdx.x;
  const size_t rb0 = (size_t)blockIdx.x * 64;          // row index, tile 0
  const size_t rb1 = (size_t)(blockIdx.x + 256) * 64;  // row index, tile 1
  const float* const h0 = hid + rb0 * Hn;              // element base, tile 0
  const float* const h1 = hid + rb1 * Hn;              // element base, tile 1
  const int wid = t >> 6, lane = t & 63;
  const int l15 = lane & 15, l4 = lane >> 4;
  const int colBase = wid * 48;

  // staging map: thread t owns row = t>>4, 16-float slice ssl = t&15
  const int srow = t >> 4;
  const int ssl = t & 15;
  const int sgoff = srow * Hn + ssl * 16;          // per-thread offset in tile
  const int wslot0 = (ssl * 2) ^ (srow & 7);       // 16B slots, XOR swizzle
  const int wslot1 = (ssl * 2 + 1) ^ (srow & 7);
  unsigned short* const awr = &As[0][0] + srow * 256;   // buf stride 64*256

  // A frag read: row = mi*16+l15 (stride 256 shorts), slot = (ks*4+l4)^aswz
  const int aswz = l15 & 7;

  // B: packed chunks; ntile = wid*3 + ni; per-kstep stride 512 shorts
  const unsigned short* bp0 = &WBp[((size_t)(wid * 3 + 0) * 24 * 64 + lane) * 8];
  const unsigned short* bp1 = &WBp[((size_t)(wid * 3 + 1) * 24 * 64 + lane) * 8];
  const unsigned short* bp2 = &WBp[((size_t)(wid * 3 + 2) * 24 * 64 + lane) * 8];

  f32x4 acc[4][3];
#pragma unroll
  for (int mi = 0; mi < 4; ++mi)
#pragma unroll
    for (int ni = 0; ni < 3; ++ni) acc[mi][ni] = (f32x4){0.f, 0.f, 0.f, 0.f};

  // ---- prologue: stage tile0 chunk0; load B(kk=0)
  {
    const float* hs = h0 + sgoff;
    float4 a0 = *reinterpret_cast<const float4*>(hs);
    float4 a1 = *reinterpret_cast<const float4*>(hs + 4);
    float4 a2 = *reinterpret_cast<const float4*>(hs + 8);
    float4 a3 = *reinterpret_cast<const float4*>(hs + 12);
    *reinterpret_cast<u16x8*>(awr + wslot0 * 8) = cvt8(a0, a1);
    *reinterpret_cast<u16x8*>(awr + wslot1 * 8) = cvt8(a2, a3);
  }
  bf16x8 bcur[3], bnxt[3];
  bcur[0] = *reinterpret_cast<const bf16x8*>(bp0);
  bcur[1] = *reinterpret_cast<const bf16x8*>(bp1);
  bcur[2] = *reinterpret_cast<const bf16x8*>(bp2);
  asm volatile("s_waitcnt lgkmcnt(0)" ::: "memory");
  __builtin_amdgcn_s_barrier();
  __builtin_amdgcn_sched_barrier(0);

#pragma unroll
  for (int c = 0; c < 6; ++c) {                    // 6 chunks = 2 tiles x 3
    // 1. issue next chunk's A loads (in flight across the 8 k-steps)
    float4 n0, n1, n2, n3;
    if (c < 5) {
      const float* hs = ((c + 1 < 3) ? h0 : h1) + sgoff + ((c + 1) % 3) * 256;
      n0 = *reinterpret_cast<const float4*>(hs);
      n1 = *reinterpret_cast<const float4*>(hs + 4);
      n2 = *reinterpret_cast<const float4*>(hs + 8);
      n3 = *reinterpret_cast<const float4*>(hs + 12);
    }
    // 2. eight k-steps on current buffer
#pragma unroll
    for (int ks = 0; ks < 8; ++ks) {
      bf16x8 af[4];
#pragma unroll
      for (int mi = 0; mi < 4; ++mi)
        af[mi] = *reinterpret_cast<const bf16x8*>(
            &As[c & 1][mi * 4096 + l15 * 256 + (((ks * 4 + l4) ^ aswz)) * 8]);
      // depth-1 B prefetch, compile-time next index
      const int cm = c % 3;
      int kkn; bool have = true;
      if (ks < 7) kkn = cm * 8 + ks + 1;
      else if (cm < 2) kkn = cm * 8 + 8;
      else { kkn = 0; have = (c != 5); }
      if (have) {
        bnxt[0] = *reinterpret_cast<const bf16x8*>(bp0 + kkn * 512);
        bnxt[1] = *reinterpret_cast<const bf16x8*>(bp1 + kkn * 512);
        bnxt[2] = *reinterpret_cast<const bf16x8*>(bp2 + kkn * 512);
      }
      __builtin_amdgcn_s_setprio(1);
#pragma unroll
      for (int mi = 0; mi < 4; ++mi)
#pragma unroll
        for (int ni = 0; ni < 3; ++ni)
          acc[mi][ni] = __builtin_amdgcn_mfma_f32_16x16x32_bf16(
              af[mi], bcur[ni], acc[mi][ni], 0, 0, 0);
      __builtin_amdgcn_s_setprio(0);
#pragma unroll
      for (int ni = 0; ni < 3; ++ni) bcur[ni] = bnxt[ni];
    }
    // 3. convert + write next chunk into the other buffer
    if (c < 5) {
      unsigned short* aw = &As[(c + 1) & 1][0] + srow * 256;
      *reinterpret_cast<u16x8*>(aw + wslot0 * 8) = cvt8(n0, n1);
      *reinterpret_cast<u16x8*>(aw + wslot1 * 8) = cvt8(n2, n3);
    }
    // 4. LDS-drain barrier only; vmem loads stay in flight
    asm volatile("s_waitcnt lgkmcnt(0)" ::: "memory");
    __builtin_amdgcn_s_barrier();
    __builtin_amdgcn_sched_barrier(0);
    // 5. tile boundary: fused epilogue, reset acc
    if (c == 2 || c == 5) {
      score_epilogue(acc, bbias, vvec, scores, scpart,
                     (c == 2) ? rb0 : rb1, wid, l15, l4, colBase, t);
      if (c == 2) {
#pragma unroll
        for (int mi = 0; mi < 4; ++mi)
#pragma unroll
          for (int ni = 0; ni < 3; ++ni) acc[mi][ni] = (f32x4){0.f, 0.f, 0.f, 0.f};
      }
    }
  }
}

// ---------------- kernel 4: per-(b,m) segment softmax + pooling
__global__ __launch_bounds__(256) void pool_kernel(
    const float* __restrict__ hid, const float* __restrict__ scores,
    const unsigned char* __restrict__ segv, const int* __restrict__ nsep,
    float* __restrict__ out) {
  int bm = blockIdx.x;
  int b = bm / Mn, m = bm % Mn;
  int t = threadIdx.x;
  __shared__ float wLds[Sn];
  __shared__ float red[256];
  __shared__ int ired[256];
  const float NEG = -1e30f;

  int base = b * Sn;
  unsigned char mg = (unsigned char)m;
  unsigned char g0 = segv[base + t], g1 = segv[base + 256 + t];
  bool v0 = (g0 == mg), v1 = (g1 == mg);
  float s0 = v0 ? scores[base + t] : NEG;
  float s1 = v1 ? scores[base + 256 + t] : NEG;

  red[t] = fmaxf(s0, s1);
  __syncthreads();
  for (int o = 128; o > 0; o >>= 1) {
    if (t < o) red[t] = fmaxf(red[t], red[t + o]);
    __syncthreads();
  }
  float gmax = red[0];
  __syncthreads();

  size_t obase = (size_t)bm * Hn;
  if (gmax <= -0.5e30f) {
    int nb = nsep[b];
    float a0 = 0.f, a1 = 0.f, a2 = 0.f;
    if (m == 0 && nb == 0) {
      const float* hp = hid + (size_t)base * Hn;
      a0 = hp[t]; a1 = hp[t + 256]; a2 = hp[t + 512];
    }
    out[obase + t] = a0; out[obase + 256 + t] = a1; out[obase + 512 + t] = a2;
    return;
  }

  float e0 = v0 ? expf(s0 - gmax) : 0.f;
  float e1 = v1 ? expf(s1 - gmax) : 0.f;
  red[t] = e0 + e1;
  __syncthreads();
  for (int o = 128; o > 0; o >>= 1) {
    if (t < o) red[t] += red[t + o];
    __syncthreads();
  }
  float inv = 1.f / red[0];
  __syncthreads();
  wLds[t] = e0 * inv;
  wLds[256 + t] = e1 * inv;

  ired[t] = min(v0 ? t : 0x7fffffff, v1 ? (256 + t) : 0x7fffffff);
  __syncthreads();
  for (int o = 128; o > 0; o >>= 1) {
    if (t < o) ired[t] = min(ired[t], ired[t + o]);
    __syncthreads();
  }
  int start = ired[0];
  __syncthreads();
  ired[t] = max(v0 ? t : -1, v1 ? (256 + t) : -1);
  __syncthreads();
  for (int o = 128; o > 0; o >>= 1) {
    if (t < o) ired[t] = max(ired[t], ired[t + o]);
    __syncthreads();
  }
  int end = ired[0];
  __syncthreads();

  float a0 = 0.f, a1 = 0.f, a2 = 0.f;
  for (int s = start; s <= end; ++s) {
    float w = wLds[s];
    if (w != 0.f) {
      const float* hp = hid + (size_t)(base + s) * Hn;
      a0 += w * hp[t];
      a1 += w * hp[t + 256];
      a2 += w * hp[t + 512];
    }
  }
  out[obase + t] = a0;
  out[obase + 256 + t] = a1;
  out[obase + 512 + t] = a2;
}

// ---------------- launch
extern "C" void kernel_launch(void* const* d_in, const int* in_sizes, int n_in,
                              void* d_out, int out_size, void* d_ws, size_t ws_size,
                              hipStream_t stream) {
  const float* hidden = (const float*)d_in[0];
  const int* ids      = (const int*)d_in[1];
  const float* W      = (const float*)d_in[2];
  const float* bbias  = (const float*)d_in[3];
  const float* vvec   = (const float*)d_in[4];

  char* ws = (char*)d_ws;
  unsigned short* WBp  = (unsigned short*)(ws);            // 1,179,648 B
  float* scores        = (float*)(ws + 1179648);
  unsigned char* segv  = (unsigned char*)(ws + 1310720);
  int* nsep            = (int*)(ws + 1343488);

  convw_kernel<<<288, 256, 0, stream>>>(W, WBp);
  segscan_kernel<<<Bn, Sn, 0, stream>>>(ids, segv, nsep);
  score_gemm_kernel<<<256, 1024, 0, stream>>>(hidden, WBp, bbias, vvec, scores);
  pool_kernel<<<Bn * Mn, 256, 0, stream>>>(hidden, scores, segv, nsep, (float*)d_out);
}

// Round 8
// 125.751 us; speedup vs baseline: 1.0022x; 1.0022x over previous
//
#include <hip/hip_runtime.h>

// Segment attention pooling, MI355X (gfx950).
// convw_pack (fp32 W -> bf16, MFMA-fragment order) ; segscan ;
// score_gemm (round-5 skeleton: whole A-tile LDS-resident, barrier-free
// K-loop, 16 waves; + depth-1 A-frag prefetch, depth-2 B prefetch) ; pool.

#define SEP_ID 102
#define Bn 64
#define Sn 512
#define Hn 768
#define Mn 21
#define BS (Bn * Sn)

typedef __attribute__((ext_vector_type(8))) short bf16x8;
typedef __attribute__((ext_vector_type(8))) unsigned short u16x8;
typedef __attribute__((ext_vector_type(4))) float f32x4;

__device__ inline unsigned short f2bf(float x) {
  unsigned int u = __builtin_bit_cast(unsigned int, x);
  u += 0x7fffu + ((u >> 16) & 1u);   // RNE
  return (unsigned short)(u >> 16);
}

__device__ inline u16x8 cvt8(float4 a, float4 b) {
  u16x8 r;
  r[0] = f2bf(a.x); r[1] = f2bf(a.y); r[2] = f2bf(a.z); r[3] = f2bf(a.w);
  r[4] = f2bf(b.x); r[5] = f2bf(b.y); r[6] = f2bf(b.z); r[7] = f2bf(b.w);
  return r;
}

__device__ inline float tanh_fast(float x) {
  float e = __builtin_amdgcn_exp2f(x * 2.885390081777927f); // 2*log2(e)
  return 1.f - 2.f * __builtin_amdgcn_rcpf(e + 1.f);
}

// ---------------- kernel 1: W fp32 -> bf16, packed in MFMA B-fragment order.
// chunk c = (ntile*24 + kstep)*64 + lane; holds W[ntile*16 + (lane&15)]
// [kstep*32 + (lane>>4)*8 ..+8]  -> score_gemm B loads are lane-contiguous.
__global__ void convw_kernel(const float* __restrict__ W, unsigned short* __restrict__ WBp) {
  int c = blockIdx.x * 256 + threadIdx.x;   // 73728 chunks, grid 288
  int nt = c / 1536;
  int r  = c % 1536;
  int ks = r >> 6;
  int ln = r & 63;
  int col = nt * 16 + (ln & 15);
  int k0  = ks * 32 + (ln >> 4) * 8;
  const float* src = &W[col * Hn + k0];
  float4 a = *reinterpret_cast<const float4*>(src);
  float4 b = *reinterpret_cast<const float4*>(src + 4);
  *reinterpret_cast<u16x8*>(&WBp[(size_t)c * 8]) = cvt8(a, b);
}

// ---------------- kernel 2: per-batch segment scan
__global__ void segscan_kernel(const int* __restrict__ ids,
                               unsigned char* __restrict__ segv,
                               int* __restrict__ nsep) {
  int b = blockIdx.x;
  int s = threadIdx.x;
  __shared__ int cs[Sn];
  int sep = (ids[b * Sn + s] == SEP_ID) ? 1 : 0;
  cs[s] = sep;
  __syncthreads();
  for (int off = 1; off < Sn; off <<= 1) {
    int add = (s >= off) ? cs[s - off] : 0;
    __syncthreads();
    cs[s] += add;
    __syncthreads();
  }
  int csum = cs[s];
  int nb = cs[Sn - 1];
  int seg = csum - sep;
  bool valid = (!sep) && (s >= 1) && (seg < nb) && (seg < Mn);
  segv[b * Sn + s] = valid ? (unsigned char)seg : (unsigned char)0xFF;
  if (s == 0) nsep[b] = nb;
}

// ---------------- kernel 3: scores = v . tanh(hidden @ W^T + b)
// 1024 thr = 16 waves, block = 64 rows x 768 cols, wave = 64 rows x 48 cols.
// Prologue: stage whole 64x768 A-tile (fp32->bf16) into LDS, ONE barrier.
// K-loop: 24 steps, NO barriers (A read-only; waves free-run and desync).
// A-frags: depth-1 LDS prefetch (afc/afn). B: packed WBp, depth-2 prefetch.
__global__ __launch_bounds__(1024, 4) void score_gemm_kernel(
    const float* __restrict__ hid, const unsigned short* __restrict__ WBp,
    const float* __restrict__ bbias, const float* __restrict__ vvec,
    float* __restrict__ scores) {
  __shared__ __align__(16) unsigned short As[64 * 768];   // 98304 B
  __shared__ float scpart[16][64];

  const int t = threadIdx.x;
  const size_t rowBase = (size_t)blockIdx.x * 64;
  const int wid = t >> 6, lane = t & 63;
  const int l15 = lane & 15, l4 = lane >> 4;
  const int colBase = wid * 48;

  // ---- prologue: stage A (row = t>>4, 16B chunk scloc = t&15, one chunk per
  // each of the 6 K-chunks of 128). XOR-swizzle chunk ^ (row&7).
  {
    const int srow = t >> 4;
    const int scloc = t & 15;
    const float* hsrc = &hid[(rowBase + srow) * Hn + scloc * 8];
    unsigned short* const arow = &As[srow * Hn];
    const int swz = srow & 7;
    float4 p[6][2];
#pragma unroll
    for (int cc = 0; cc < 6; ++cc) {
      p[cc][0] = *reinterpret_cast<const float4*>(hsrc + cc * 128);
      p[cc][1] = *reinterpret_cast<const float4*>(hsrc + cc * 128 + 4);
    }
#pragma unroll
    for (int cc = 0; cc < 6; ++cc)
      *reinterpret_cast<u16x8*>(arow + ((cc * 16 + scloc) ^ swz) * 8) =
          cvt8(p[cc][0], p[cc][1]);
  }
  __syncthreads();

  // A frag read base: row = mi*16 + l15, chunk = (kk*4 + l4) ^ (l15&7)
  const unsigned short* const afrow = &As[l15 * Hn];
  const int aswz = l15 & 7;
  // B: packed fragment chunks, ntile = wid*3 + ni, per-kstep stride 512 shorts
  const unsigned short* bp0 = &WBp[((size_t)(wid * 3 + 0) * 24 * 64 + lane) * 8];
  const unsigned short* bp1 = &WBp[((size_t)(wid * 3 + 1) * 24 * 64 + lane) * 8];
  const unsigned short* bp2 = &WBp[((size_t)(wid * 3 + 2) * 24 * 64 + lane) * 8];

  f32x4 acc[4][3];
#pragma unroll
  for (int mi = 0; mi < 4; ++mi)
#pragma unroll
    for (int ni = 0; ni < 3; ++ni) acc[mi][ni] = (f32x4){0.f, 0.f, 0.f, 0.f};

  // B ring (depth 2) + A-frag double buffer (depth 1)
  bf16x8 b0[3], b1[3], b2[3];
  b0[0] = *reinterpret_cast<const bf16x8*>(bp0);
  b0[1] = *reinterpret_cast<const bf16x8*>(bp1);
  b0[2] = *reinterpret_cast<const bf16x8*>(bp2);
  b1[0] = *reinterpret_cast<const bf16x8*>(bp0 + 512);
  b1[1] = *reinterpret_cast<const bf16x8*>(bp1 + 512);
  b1[2] = *reinterpret_cast<const bf16x8*>(bp2 + 512);

  bf16x8 afc[4], afn[4];
#pragma unroll
  for (int mi = 0; mi < 4; ++mi)
    afc[mi] = *reinterpret_cast<const bf16x8*>(
        &afrow[mi * 16 * Hn + ((l4 ^ aswz)) * 8]);   // kk=0 frags

#pragma unroll
  for (int kk = 0; kk < 24; ++kk) {
    // prefetch next k-step's A frags from LDS (hides ds_read latency)
    if (kk < 23) {
#pragma unroll
      for (int mi = 0; mi < 4; ++mi)
        afn[mi] = *reinterpret_cast<const bf16x8*>(
            &afrow[mi * 16 * Hn + ((((kk + 1) * 4 + l4) ^ aswz)) * 8]);
    }
    // prefetch B two k-steps ahead (L2 latency cover)
    if (kk + 2 < 24) {
      b2[0] = *reinterpret_cast<const bf16x8*>(bp0 + (kk + 2) * 512);
      b2[1] = *reinterpret_cast<const bf16x8*>(bp1 + (kk + 2) * 512);
      b2[2] = *reinterpret_cast<const bf16x8*>(bp2 + (kk + 2) * 512);
    }
    __builtin_amdgcn_s_setprio(1);
#pragma unroll
    for (int mi = 0; mi < 4; ++mi)
#pragma unroll
      for (int ni = 0; ni < 3; ++ni)
        acc[mi][ni] = __builtin_amdgcn_mfma_f32_16x16x32_bf16(
            afc[mi], b0[ni], acc[mi][ni], 0, 0, 0);
    __builtin_amdgcn_s_setprio(0);
#pragma unroll
    for (int mi = 0; mi < 4; ++mi) afc[mi] = afn[mi];
#pragma unroll
    for (int ni = 0; ni < 3; ++ni) { b0[ni] = b1[ni]; b1[ni] = b2[ni]; }
  }

  // ---- fused epilogue: tanh(pre + b) * v over the wave's 48 cols
  float sc[4][4];
#pragma unroll
  for (int mi = 0; mi < 4; ++mi)
#pragma unroll
    for (int r = 0; r < 4; ++r) sc[mi][r] = 0.f;
#pragma unroll
  for (int ni = 0; ni < 3; ++ni) {
    int col = colBase + ni * 16 + l15;
    float vv = vvec[col];
    float bb = bbias[col];
#pragma unroll
    for (int mi = 0; mi < 4; ++mi)
#pragma unroll
      for (int r = 0; r < 4; ++r)
        sc[mi][r] += tanh_fast(acc[mi][ni][r] + bb) * vv;
  }
#pragma unroll
  for (int off = 1; off < 16; off <<= 1)
#pragma unroll
    for (int mi = 0; mi < 4; ++mi)
#pragma unroll
      for (int r = 0; r < 4; ++r)
        sc[mi][r] += __shfl_xor(sc[mi][r], off, 64);
  if (l15 == 0) {
#pragma unroll
    for (int mi = 0; mi < 4; ++mi)
#pragma unroll
      for (int r = 0; r < 4; ++r)
        scpart[wid][mi * 16 + l4 * 4 + r] = sc[mi][r];
  }
  __syncthreads();
  if (t < 64) {
    float s = 0.f;
#pragma unroll
    for (int w = 0; w < 16; ++w) s += scpart[w][t];
    scores[rowBase + t] = s;
  }
}

// ---------------- kernel 4: per-(b,m) segment softmax + pooling
__global__ __launch_bounds__(256) void pool_kernel(
    const float* __restrict__ hid, const float* __restrict__ scores,
    const unsigned char* __restrict__ segv, const int* __restrict__ nsep,
    float* __restrict__ out) {
  int bm = blockIdx.x;
  int b = bm / Mn, m = bm % Mn;
  int t = threadIdx.x;
  __shared__ float wLds[Sn];
  __shared__ float red[256];
  __shared__ int ired[256];
  const float NEG = -1e30f;

  int base = b * Sn;
  unsigned char mg = (unsigned char)m;
  unsigned char g0 = segv[base + t], g1 = segv[base + 256 + t];
  bool v0 = (g0 == mg), v1 = (g1 == mg);
  float s0 = v0 ? scores[base + t] : NEG;
  float s1 = v1 ? scores[base + 256 + t] : NEG;

  red[t] = fmaxf(s0, s1);
  __syncthreads();
  for (int o = 128; o > 0; o >>= 1) {
    if (t < o) red[t] = fmaxf(red[t], red[t + o]);
    __syncthreads();
  }
  float gmax = red[0];
  __syncthreads();

  size_t obase = (size_t)bm * Hn;
  if (gmax <= -0.5e30f) {
    int nb = nsep[b];
    float a0 = 0.f, a1 = 0.f, a2 = 0.f;
    if (m == 0 && nb == 0) {
      const float* hp = hid + (size_t)base * Hn;
      a0 = hp[t]; a1 = hp[t + 256]; a2 = hp[t + 512];
    }
    out[obase + t] = a0; out[obase + 256 + t] = a1; out[obase + 512 + t] = a2;
    return;
  }

  float e0 = v0 ? expf(s0 - gmax) : 0.f;
  float e1 = v1 ? expf(s1 - gmax) : 0.f;
  red[t] = e0 + e1;
  __syncthreads();
  for (int o = 128; o > 0; o >>= 1) {
    if (t < o) red[t] += red[t + o];
    __syncthreads();
  }
  float inv = 1.f / red[0];
  __syncthreads();
  wLds[t] = e0 * inv;
  wLds[256 + t] = e1 * inv;

  ired[t] = min(v0 ? t : 0x7fffffff, v1 ? (256 + t) : 0x7fffffff);
  __syncthreads();
  for (int o = 128; o > 0; o >>= 1) {
    if (t < o) ired[t] = min(ired[t], ired[t + o]);
    __syncthreads();
  }
  int start = ired[0];
  __syncthreads();
  ired[t] = max(v0 ? t : -1, v1 ? (256 + t) : -1);
  __syncthreads();
  for (int o = 128; o > 0; o >>= 1) {
    if (t < o) ired[t] = max(ired[t], ired[t + o]);
    __syncthreads();
  }
  int end = ired[0];
  __syncthreads();

  float a0 = 0.f, a1 = 0.f, a2 = 0.f;
  for (int s = start; s <= end; ++s) {
    float w = wLds[s];
    if (w != 0.f) {
      const float* hp = hid + (size_t)(base + s) * Hn;
      a0 += w * hp[t];
      a1 += w * hp[t + 256];
      a2 += w * hp[t + 512];
    }
  }
  out[obase + t] = a0;
  out[obase + 256 + t] = a1;
  out[obase + 512 + t] = a2;
}

// ---------------- launch
extern "C" void kernel_launch(void* const* d_in, const int* in_sizes, int n_in,
                              void* d_out, int out_size, void* d_ws, size_t ws_size,
                              hipStream_t stream) {
  const float* hidden = (const float*)d_in[0];
  const int* ids      = (const int*)d_in[1];
  const float* W      = (const float*)d_in[2];
  const float* bbias  = (const float*)d_in[3];
  const float* vvec   = (const float*)d_in[4];

  char* ws = (char*)d_ws;
  unsigned short* WBp  = (unsigned short*)(ws);            // 1,179,648 B
  float* scores        = (float*)(ws + 1179648);
  unsigned char* segv  = (unsigned char*)(ws + 1310720);
  int* nsep            = (int*)(ws + 1343488);

  convw_kernel<<<288, 256, 0, stream>>>(W, WBp);
  segscan_kernel<<<Bn, Sn, 0, stream>>>(ids, segv, nsep);
  score_gemm_kernel<<<BS / 64, 1024, 0, stream>>>(hidden, WBp, bbias, vvec, scores);
  pool_kernel<<<Bn * Mn, 256, 0, stream>>>(hidden, scores, segv, nsep, (float*)d_out);
}

// Round 10
// 91.254 us; speedup vs baseline: 1.3810x; 1.3780x over previous
//
#include <hip/hip_runtime.h>

// Segment attention pooling, MI355X (gfx950).
// convw_pack (fp32 W -> bf16, MFMA-fragment order) ; segscan ;
// score_gemm (whole A-tile LDS-resident, barrier-free K-loop, 16 waves,
// nontemporal A staging, depth-4 B ring) ; pool.

#define SEP_ID 102
#define Bn 64
#define Sn 512
#define Hn 768
#define Mn 21
#define BS (Bn * Sn)

typedef __attribute__((ext_vector_type(8))) short bf16x8;
typedef __attribute__((ext_vector_type(8))) unsigned short u16x8;
typedef __attribute__((ext_vector_type(4))) float f32x4;

__device__ inline unsigned short f2bf(float x) {
  unsigned int u = __builtin_bit_cast(unsigned int, x);
  u += 0x7fffu + ((u >> 16) & 1u);   // RNE
  return (unsigned short)(u >> 16);
}

__device__ inline u16x8 cvt8v(f32x4 a, f32x4 b) {
  u16x8 r;
  r[0] = f2bf(a[0]); r[1] = f2bf(a[1]); r[2] = f2bf(a[2]); r[3] = f2bf(a[3]);
  r[4] = f2bf(b[0]); r[5] = f2bf(b[1]); r[6] = f2bf(b[2]); r[7] = f2bf(b[3]);
  return r;
}

__device__ inline float tanh_fast(float x) {
  float e = __builtin_amdgcn_exp2f(x * 2.885390081777927f); // 2*log2(e)
  return 1.f - 2.f * __builtin_amdgcn_rcpf(e + 1.f);
}

// ---------------- kernel 1: W fp32 -> bf16, packed in MFMA B-fragment order.
// chunk c = (ntile*24 + kstep)*64 + lane; holds W[ntile*16 + (lane&15)]
// [kstep*32 + (lane>>4)*8 ..+8]  -> score_gemm B loads are lane-contiguous.
__global__ void convw_kernel(const float* __restrict__ W, unsigned short* __restrict__ WBp) {
  int c = blockIdx.x * 256 + threadIdx.x;   // 73728 chunks, grid 288
  int nt = c / 1536;
  int r  = c % 1536;
  int ks = r >> 6;
  int ln = r & 63;
  int col = nt * 16 + (ln & 15);
  int k0  = ks * 32 + (ln >> 4) * 8;
  const f32x4* src = reinterpret_cast<const f32x4*>(&W[col * Hn + k0]);
  f32x4 a = src[0];
  f32x4 b = src[1];
  *reinterpret_cast<u16x8*>(&WBp[(size_t)c * 8]) = cvt8v(a, b);
}

// ---------------- kernel 2: per-batch segment scan
__global__ void segscan_kernel(const int* __restrict__ ids,
                               unsigned char* __restrict__ segv,
                               int* __restrict__ nsep) {
  int b = blockIdx.x;
  int s = threadIdx.x;
  __shared__ int cs[Sn];
  int sep = (ids[b * Sn + s] == SEP_ID) ? 1 : 0;
  cs[s] = sep;
  __syncthreads();
  for (int off = 1; off < Sn; off <<= 1) {
    int add = (s >= off) ? cs[s - off] : 0;
    __syncthreads();
    cs[s] += add;
    __syncthreads();
  }
  int csum = cs[s];
  int nb = cs[Sn - 1];
  int seg = csum - sep;
  bool valid = (!sep) && (s >= 1) && (seg < nb) && (seg < Mn);
  segv[b * Sn + s] = valid ? (unsigned char)seg : (unsigned char)0xFF;
  if (s == 0) nsep[b] = nb;
}

// ---------------- kernel 3: scores = v . tanh(hidden @ W^T + b)
// 1024 thr = 16 waves, block = 64 rows x 768 cols, wave = 64 rows x 48 cols.
// Prologue: stage whole 64x768 A-tile (fp32->bf16, NONTEMPORAL loads -- A has
// zero L2 reuse; keep it from evicting the shared B working set) into LDS,
// one barrier. K-loop: 24 steps, NO barriers (A read-only; waves free-run).
// B: packed WBp from L2, 4-slot ring (issue kk+3 at step kk).
__global__ __launch_bounds__(1024, 4) void score_gemm_kernel(
    const float* __restrict__ hid, const unsigned short* __restrict__ WBp,
    const float* __restrict__ bbias, const float* __restrict__ vvec,
    float* __restrict__ scores) {
  __shared__ __align__(16) unsigned short As[64 * 768];   // 98304 B
  __shared__ float scpart[16][64];

  const int t = threadIdx.x;
  const size_t rowBase = (size_t)blockIdx.x * 64;
  const int wid = t >> 6, lane = t & 63;
  const int l15 = lane & 15, l4 = lane >> 4;
  const int colBase = wid * 48;

  // ---- prologue: stage A (row = t>>4, 16B chunk scloc = t&15, one chunk per
  // each of the 6 K-chunks of 128). XOR-swizzle chunk ^ (row&7).
  {
    const int srow = t >> 4;
    const int scloc = t & 15;
    const f32x4* hsrc = reinterpret_cast<const f32x4*>(
        &hid[(rowBase + srow) * Hn + scloc * 8]);   // f32x4 units
    unsigned short* const arow = &As[srow * Hn];
    const int swz = srow & 7;
    f32x4 p[6][2];
#pragma unroll
    for (int cc = 0; cc < 6; ++cc) {
      p[cc][0] = __builtin_nontemporal_load(hsrc + cc * 32);
      p[cc][1] = __builtin_nontemporal_load(hsrc + cc * 32 + 1);
    }
#pragma unroll
    for (int cc = 0; cc < 6; ++cc)
      *reinterpret_cast<u16x8*>(arow + ((cc * 16 + scloc) ^ swz) * 8) =
          cvt8v(p[cc][0], p[cc][1]);
  }
  __syncthreads();

  // A frag read base: row = mi*16 + l15, chunk = (kk*4 + l4) ^ (l15&7)
  const unsigned short* const afrow = &As[l15 * Hn];
  const int aswz = l15 & 7;
  // B: packed fragment chunks, ntile = wid*3 + ni, per-kstep stride 512 shorts
  const unsigned short* bp0 = &WBp[((size_t)(wid * 3 + 0) * 24 * 64 + lane) * 8];
  const unsigned short* bp1 = &WBp[((size_t)(wid * 3 + 1) * 24 * 64 + lane) * 8];
  const unsigned short* bp2 = &WBp[((size_t)(wid * 3 + 2) * 24 * 64 + lane) * 8];

  f32x4 acc[4][3];
#pragma unroll
  for (int mi = 0; mi < 4; ++mi)
#pragma unroll
    for (int ni = 0; ni < 3; ++ni) acc[mi][ni] = (f32x4){0.f, 0.f, 0.f, 0.f};

  // B ring, 4 slots (depth 3 in flight + 1 in use). Full unroll -> static idx.
  bf16x8 br[4][3];
#pragma unroll
  for (int s = 0; s < 3; ++s) {
    br[s][0] = *reinterpret_cast<const bf16x8*>(bp0 + s * 512);
    br[s][1] = *reinterpret_cast<const bf16x8*>(bp1 + s * 512);
    br[s][2] = *reinterpret_cast<const bf16x8*>(bp2 + s * 512);
  }

#pragma unroll
  for (int kk = 0; kk < 24; ++kk) {
    bf16x8 af[4];
#pragma unroll
    for (int mi = 0; mi < 4; ++mi)
      af[mi] = *reinterpret_cast<const bf16x8*>(
          &afrow[mi * 16 * Hn + (((kk * 4 + l4) ^ aswz)) * 8]);
    if (kk + 3 < 24) {
      const int sl = (kk + 3) & 3;
      br[sl][0] = *reinterpret_cast<const bf16x8*>(bp0 + (kk + 3) * 512);
      br[sl][1] = *reinterpret_cast<const bf16x8*>(bp1 + (kk + 3) * 512);
      br[sl][2] = *reinterpret_cast<const bf16x8*>(bp2 + (kk + 3) * 512);
    }
    const int cu = kk & 3;
    __builtin_amdgcn_s_setprio(1);
#pragma unroll
    for (int mi = 0; mi < 4; ++mi)
#pragma unroll
      for (int ni = 0; ni < 3; ++ni)
        acc[mi][ni] = __builtin_amdgcn_mfma_f32_16x16x32_bf16(
            af[mi], br[cu][ni], acc[mi][ni], 0, 0, 0);
    __builtin_amdgcn_s_setprio(0);
  }

  // ---- fused epilogue: tanh(pre + b) * v over the wave's 48 cols
  float sc[4][4];
#pragma unroll
  for (int mi = 0; mi < 4; ++mi)
#pragma unroll
    for (int r = 0; r < 4; ++r) sc[mi][r] = 0.f;
#pragma unroll
  for (int ni = 0; ni < 3; ++ni) {
    int col = colBase + ni * 16 + l15;
    float vv = vvec[col];
    float bb = bbias[col];
#pragma unroll
    for (int mi = 0; mi < 4; ++mi)
#pragma unroll
      for (int r = 0; r < 4; ++r)
        sc[mi][r] += tanh_fast(acc[mi][ni][r] + bb) * vv;
  }
#pragma unroll
  for (int off = 1; off < 16; off <<= 1)
#pragma unroll
    for (int mi = 0; mi < 4; ++mi)
#pragma unroll
      for (int r = 0; r < 4; ++r)
        sc[mi][r] += __shfl_xor(sc[mi][r], off, 64);
  if (l15 == 0) {
#pragma unroll
    for (int mi = 0; mi < 4; ++mi)
#pragma unroll
      for (int r = 0; r < 4; ++r)
        scpart[wid][mi * 16 + l4 * 4 + r] = sc[mi][r];
  }
  __syncthreads();
  if (t < 64) {
    float s = 0.f;
#pragma unroll
    for (int w = 0; w < 16; ++w) s += scpart[w][t];
    scores[rowBase + t] = s;
  }
}

// ---------------- kernel 4: per-(b,m) segment softmax + pooling
__global__ __launch_bounds__(256) void pool_kernel(
    const float* __restrict__ hid, const float* __restrict__ scores,
    const unsigned char* __restrict__ segv, const int* __restrict__ nsep,
    float* __restrict__ out) {
  int bm = blockIdx.x;
  int b = bm / Mn, m = bm % Mn;
  int t = threadIdx.x;
  __shared__ float wLds[Sn];
  __shared__ float red[256];
  __shared__ int ired[256];
  const float NEG = -1e30f;

  int base = b * Sn;
  unsigned char mg = (unsigned char)m;
  unsigned char g0 = segv[base + t], g1 = segv[base + 256 + t];
  bool v0 = (g0 == mg), v1 = (g1 == mg);
  float s0 = v0 ? scores[base + t] : NEG;
  float s1 = v1 ? scores[base + 256 + t] : NEG;

  red[t] = fmaxf(s0, s1);
  __syncthreads();
  for (int o = 128; o > 0; o >>= 1) {
    if (t < o) red[t] = fmaxf(red[t], red[t + o]);
    __syncthreads();
  }
  float gmax = red[0];
  __syncthreads();

  size_t obase = (size_t)bm * Hn;
  if (gmax <= -0.5e30f) {
    int nb = nsep[b];
    float a0 = 0.f, a1 = 0.f, a2 = 0.f;
    if (m == 0 && nb == 0) {
      const float* hp = hid + (size_t)base * Hn;
      a0 = hp[t]; a1 = hp[t + 256]; a2 = hp[t + 512];
    }
    out[obase + t] = a0; out[obase + 256 + t] = a1; out[obase + 512 + t] = a2;
    return;
  }

  float e0 = v0 ? expf(s0 - gmax) : 0.f;
  float e1 = v1 ? expf(s1 - gmax) : 0.f;
  red[t] = e0 + e1;
  __syncthreads();
  for (int o = 128; o > 0; o >>= 1) {
    if (t < o) red[t] += red[t + o];
    __syncthreads();
  }
  float inv = 1.f / red[0];
  __syncthreads();
  wLds[t] = e0 * inv;
  wLds[256 + t] = e1 * inv;

  ired[t] = min(v0 ? t : 0x7fffffff, v1 ? (256 + t) : 0x7fffffff);
  __syncthreads();
  for (int o = 128; o > 0; o >>= 1) {
    if (t < o) ired[t] = min(ired[t], ired[t + o]);
    __syncthreads();
  }
  int start = ired[0];
  __syncthreads();
  ired[t] = max(v0 ? t : -1, v1 ? (256 + t) : -1);
  __syncthreads();
  for (int o = 128; o > 0; o >>= 1) {
    if (t < o) ired[t] = max(ired[t], ired[t + o]);
    __syncthreads();
  }
  int end = ired[0];
  __syncthreads();

  float a0 = 0.f, a1 = 0.f, a2 = 0.f;
  for (int s = start; s <= end; ++s) {
    float w = wLds[s];
    if (w != 0.f) {
      const float* hp = hid + (size_t)(base + s) * Hn;
      a0 += w * hp[t];
      a1 += w * hp[t + 256];
      a2 += w * hp[t + 512];
    }
  }
  out[obase + t] = a0;
  out[obase + 256 + t] = a1;
  out[obase + 512 + t] = a2;
}

// ---------------- launch
extern "C" void kernel_launch(void* const* d_in, const int* in_sizes, int n_in,
                              void* d_out, int out_size, void* d_ws, size_t ws_size,
                              hipStream_t stream) {
  const float* hidden = (const float*)d_in[0];
  const int* ids      = (const int*)d_in[1];
  const float* W      = (const float*)d_in[2];
  const float* bbias  = (const float*)d_in[3];
  const float* vvec   = (const float*)d_in[4];

  char* ws = (char*)d_ws;
  unsigned short* WBp  = (unsigned short*)(ws);            // 1,179,648 B
  float* scores        = (float*)(ws + 1179648);
  unsigned char* segv  = (unsigned char*)(ws + 1310720);
  int* nsep            = (int*)(ws + 1343488);

  convw_kernel<<<288, 256, 0, stream>>>(W, WBp);
  segscan_kernel<<<Bn, Sn, 0, stream>>>(ids, segv, nsep);
  score_gemm_kernel<<<BS / 64, 1024, 0, stream>>>(hidden, WBp, bbias, vvec, scores);
  pool_kernel<<<Bn * Mn, 256, 0, stream>>>(hidden, scores, segv, nsep, (float*)d_out);
}

// Round 11
// 77.579 us; speedup vs baseline: 1.6245x; 1.1763x over previous
//
#include <hip/hip_runtime.h>

// Segment attention pooling, MI355X (gfx950).
// convw_pack (fp32 W -> bf16, MFMA-fragment order) ; segscan ;
// score_gemm (whole A-tile LDS-resident, barrier-free K-loop, 16 waves,
// per-wave software pipeline: A-frag dbuf + B depth-1 dbuf) ; pool.

#define SEP_ID 102
#define Bn 64
#define Sn 512
#define Hn 768
#define Mn 21
#define BS (Bn * Sn)

typedef __attribute__((ext_vector_type(8))) short bf16x8;
typedef __attribute__((ext_vector_type(8))) unsigned short u16x8;
typedef __attribute__((ext_vector_type(4))) float f32x4;

__device__ inline unsigned short f2bf(float x) {
  unsigned int u = __builtin_bit_cast(unsigned int, x);
  u += 0x7fffu + ((u >> 16) & 1u);   // RNE
  return (unsigned short)(u >> 16);
}

__device__ inline u16x8 cvt8v(f32x4 a, f32x4 b) {
  u16x8 r;
  r[0] = f2bf(a[0]); r[1] = f2bf(a[1]); r[2] = f2bf(a[2]); r[3] = f2bf(a[3]);
  r[4] = f2bf(b[0]); r[5] = f2bf(b[1]); r[6] = f2bf(b[2]); r[7] = f2bf(b[3]);
  return r;
}

__device__ inline float tanh_fast(float x) {
  float e = __builtin_amdgcn_exp2f(x * 2.885390081777927f); // 2*log2(e)
  return 1.f - 2.f * __builtin_amdgcn_rcpf(e + 1.f);
}

// ---------------- kernel 1: W fp32 -> bf16, packed in MFMA B-fragment order.
// chunk c = (ntile*24 + kstep)*64 + lane; holds W[ntile*16 + (lane&15)]
// [kstep*32 + (lane>>4)*8 ..+8]  -> score_gemm B loads are lane-contiguous.
__global__ void convw_kernel(const float* __restrict__ W, unsigned short* __restrict__ WBp) {
  int c = blockIdx.x * 256 + threadIdx.x;   // 73728 chunks, grid 288
  int nt = c / 1536;
  int r  = c % 1536;
  int ks = r >> 6;
  int ln = r & 63;
  int col = nt * 16 + (ln & 15);
  int k0  = ks * 32 + (ln >> 4) * 8;
  const f32x4* src = reinterpret_cast<const f32x4*>(&W[col * Hn + k0]);
  f32x4 a = src[0];
  f32x4 b = src[1];
  *reinterpret_cast<u16x8*>(&WBp[(size_t)c * 8]) = cvt8v(a, b);
}

// ---------------- kernel 2: per-batch segment scan
__global__ void segscan_kernel(const int* __restrict__ ids,
                               unsigned char* __restrict__ segv,
                               int* __restrict__ nsep) {
  int b = blockIdx.x;
  int s = threadIdx.x;
  __shared__ int cs[Sn];
  int sep = (ids[b * Sn + s] == SEP_ID) ? 1 : 0;
  cs[s] = sep;
  __syncthreads();
  for (int off = 1; off < Sn; off <<= 1) {
    int add = (s >= off) ? cs[s - off] : 0;
    __syncthreads();
    cs[s] += add;
    __syncthreads();
  }
  int csum = cs[s];
  int nb = cs[Sn - 1];
  int seg = csum - sep;
  bool valid = (!sep) && (s >= 1) && (seg < nb) && (seg < Mn);
  segv[b * Sn + s] = valid ? (unsigned char)seg : (unsigned char)0xFF;
  if (s == 0) nsep[b] = nb;
}

// ---------------- kernel 3: scores = v . tanh(hidden @ W^T + b)
// 1024 thr = 16 waves, block = 64 rows x 768 cols, wave = 64 rows x 48 cols.
// Prologue: stage whole 64x768 A-tile (fp32->bf16) into LDS, one barrier.
// K-loop: 24 steps, NO block barriers; per-wave software pipeline:
//   step kk: issue ds_read af(kk+1) + global br(kk+1), sched_barrier,
//            then 12 MFMA on af(kk)/br(kk).  (loads lead use by 1 k-step)
// Register budget: af 2x16 + br 2x12 = 56 VGPR + 48 AGPR acc -> fits 128.
__global__ __launch_bounds__(1024, 4) void score_gemm_kernel(
    const float* __restrict__ hid, const unsigned short* __restrict__ WBp,
    const float* __restrict__ bbias, const float* __restrict__ vvec,
    float* __restrict__ scores) {
  __shared__ __align__(16) unsigned short As[64 * 768];   // 98304 B
  __shared__ float scpart[16][64];

  const int t = threadIdx.x;
  const size_t rowBase = (size_t)blockIdx.x * 64;
  const int wid = t >> 6, lane = t & 63;
  const int l15 = lane & 15, l4 = lane >> 4;
  const int colBase = wid * 48;

  // ---- prologue: stage A (row = t>>4, 16B chunk scloc = t&15, one chunk per
  // each of the 6 K-chunks of 128). XOR-swizzle chunk ^ (row&7).
  {
    const int srow = t >> 4;
    const int scloc = t & 15;
    const f32x4* hsrc = reinterpret_cast<const f32x4*>(
        &hid[(rowBase + srow) * Hn + scloc * 8]);   // f32x4 units
    unsigned short* const arow = &As[srow * Hn];
    const int swz = srow & 7;
    f32x4 p[6][2];
#pragma unroll
    for (int cc = 0; cc < 6; ++cc) {
      p[cc][0] = hsrc[cc * 32];
      p[cc][1] = hsrc[cc * 32 + 1];
    }
#pragma unroll
    for (int cc = 0; cc < 6; ++cc)
      *reinterpret_cast<u16x8*>(arow + ((cc * 16 + scloc) ^ swz) * 8) =
          cvt8v(p[cc][0], p[cc][1]);
  }
  __syncthreads();

  // A frag read base: row = mi*16 + l15, chunk = (kk*4 + l4) ^ (l15&7)
  const unsigned short* const afrow = &As[l15 * Hn];
  const int aswz = l15 & 7;
  // B: packed fragment chunks, ntile = wid*3 + ni, per-kstep stride 512 shorts
  const unsigned short* bp0 = &WBp[((size_t)(wid * 3 + 0) * 24 * 64 + lane) * 8];
  const unsigned short* bp1 = &WBp[((size_t)(wid * 3 + 1) * 24 * 64 + lane) * 8];
  const unsigned short* bp2 = &WBp[((size_t)(wid * 3 + 2) * 24 * 64 + lane) * 8];

  f32x4 acc[4][3];
#pragma unroll
  for (int mi = 0; mi < 4; ++mi)
#pragma unroll
    for (int ni = 0; ni < 3; ++ni) acc[mi][ni] = (f32x4){0.f, 0.f, 0.f, 0.f};

  // double buffers: afA/afB (A frags), brA/brB (B frags)
  bf16x8 afA[4], afB[4], brA[3], brB[3];
#pragma unroll
  for (int mi = 0; mi < 4; ++mi)
    afA[mi] = *reinterpret_cast<const bf16x8*>(
        &afrow[mi * 16 * Hn + ((l4 ^ aswz)) * 8]);          // kk = 0
  brA[0] = *reinterpret_cast<const bf16x8*>(bp0);
  brA[1] = *reinterpret_cast<const bf16x8*>(bp1);
  brA[2] = *reinterpret_cast<const bf16x8*>(bp2);

  // one pipeline step: load (kk+1) into afn/brn, then MFMA on afc/brc
#define STEP(kk_, afc, afn, brc, brn)                                       \
  {                                                                         \
    if ((kk_) < 23) {                                                       \
      _Pragma("unroll")                                                     \
      for (int mi = 0; mi < 4; ++mi)                                        \
        afn[mi] = *reinterpret_cast<const bf16x8*>(                         \
            &afrow[mi * 16 * Hn + ((((kk_) + 1) * 4 + l4) ^ aswz) * 8]);    \
      brn[0] = *reinterpret_cast<const bf16x8*>(bp0 + ((kk_) + 1) * 512);   \
      brn[1] = *reinterpret_cast<const bf16x8*>(bp1 + ((kk_) + 1) * 512);   \
      brn[2] = *reinterpret_cast<const bf16x8*>(bp2 + ((kk_) + 1) * 512);   \
    }                                                                       \
    __builtin_amdgcn_sched_barrier(0);                                      \
    __builtin_amdgcn_s_setprio(1);                                          \
    _Pragma("unroll")                                                       \
    for (int mi = 0; mi < 4; ++mi)                                          \
      _Pragma("unroll")                                                     \
      for (int ni = 0; ni < 3; ++ni)                                        \
        acc[mi][ni] = __builtin_amdgcn_mfma_f32_16x16x32_bf16(              \
            afc[mi], brc[ni], acc[mi][ni], 0, 0, 0);                        \
    __builtin_amdgcn_s_setprio(0);                                          \
  }

#pragma unroll
  for (int k2 = 0; k2 < 12; ++k2) {
    STEP(k2 * 2,     afA, afB, brA, brB)
    STEP(k2 * 2 + 1, afB, afA, brB, brA)
  }
#undef STEP

  // ---- fused epilogue: tanh(pre + b) * v over the wave's 48 cols
  float sc[4][4];
#pragma unroll
  for (int mi = 0; mi < 4; ++mi)
#pragma unroll
    for (int r = 0; r < 4; ++r) sc[mi][r] = 0.f;
#pragma unroll
  for (int ni = 0; ni < 3; ++ni) {
    int col = colBase + ni * 16 + l15;
    float vv = vvec[col];
    float bb = bbias[col];
#pragma unroll
    for (int mi = 0; mi < 4; ++mi)
#pragma unroll
      for (int r = 0; r < 4; ++r)
        sc[mi][r] += tanh_fast(acc[mi][ni][r] + bb) * vv;
  }
#pragma unroll
  for (int off = 1; off < 16; off <<= 1)
#pragma unroll
    for (int mi = 0; mi < 4; ++mi)
#pragma unroll
      for (int r = 0; r < 4; ++r)
        sc[mi][r] += __shfl_xor(sc[mi][r], off, 64);
  if (l15 == 0) {
#pragma unroll
    for (int mi = 0; mi < 4; ++mi)
#pragma unroll
      for (int r = 0; r < 4; ++r)
        scpart[wid][mi * 16 + l4 * 4 + r] = sc[mi][r];
  }
  __syncthreads();
  if (t < 64) {
    float s = 0.f;
#pragma unroll
    for (int w = 0; w < 16; ++w) s += scpart[w][t];
    scores[rowBase + t] = s;
  }
}

// ---------------- kernel 4: per-(b,m) segment softmax + pooling
__global__ __launch_bounds__(256) void pool_kernel(
    const float* __restrict__ hid, const float* __restrict__ scores,
    const unsigned char* __restrict__ segv, const int* __restrict__ nsep,
    float* __restrict__ out) {
  int bm = blockIdx.x;
  int b = bm / Mn, m = bm % Mn;
  int t = threadIdx.x;
  __shared__ float wLds[Sn];
  __shared__ float red[256];
  __shared__ int ired[256];
  const float NEG = -1e30f;

  int base = b * Sn;
  unsigned char mg = (unsigned char)m;
  unsigned char g0 = segv[base + t], g1 = segv[base + 256 + t];
  bool v0 = (g0 == mg), v1 = (g1 == mg);
  float s0 = v0 ? scores[base + t] : NEG;
  float s1 = v1 ? scores[base + 256 + t] : NEG;

  red[t] = fmaxf(s0, s1);
  __syncthreads();
  for (int o = 128; o > 0; o >>= 1) {
    if (t < o) red[t] = fmaxf(red[t], red[t + o]);
    __syncthreads();
  }
  float gmax = red[0];
  __syncthreads();

  size_t obase = (size_t)bm * Hn;
  if (gmax <= -0.5e30f) {
    int nb = nsep[b];
    float a0 = 0.f, a1 = 0.f, a2 = 0.f;
    if (m == 0 && nb == 0) {
      const float* hp = hid + (size_t)base * Hn;
      a0 = hp[t]; a1 = hp[t + 256]; a2 = hp[t + 512];
    }
    out[obase + t] = a0; out[obase + 256 + t] = a1; out[obase + 512 + t] = a2;
    return;
  }

  float e0 = v0 ? expf(s0 - gmax) : 0.f;
  float e1 = v1 ? expf(s1 - gmax) : 0.f;
  red[t] = e0 + e1;
  __syncthreads();
  for (int o = 128; o > 0; o >>= 1) {
    if (t < o) red[t] += red[t + o];
    __syncthreads();
  }
  float inv = 1.f / red[0];
  __syncthreads();
  wLds[t] = e0 * inv;
  wLds[256 + t] = e1 * inv;

  ired[t] = min(v0 ? t : 0x7fffffff, v1 ? (256 + t) : 0x7fffffff);
  __syncthreads();
  for (int o = 128; o > 0; o >>= 1) {
    if (t < o) ired[t] = min(ired[t], ired[t + o]);
    __syncthreads();
  }
  int start = ired[0];
  __syncthreads();
  ired[t] = max(v0 ? t : -1, v1 ? (256 + t) : -1);
  __syncthreads();
  for (int o = 128; o > 0; o >>= 1) {
    if (t < o) ired[t] = max(ired[t], ired[t + o]);
    __syncthreads();
  }
  int end = ired[0];
  __syncthreads();

  float a0 = 0.f, a1 = 0.f, a2 = 0.f;
  for (int s = start; s <= end; ++s) {
    float w = wLds[s];
    if (w != 0.f) {
      const float* hp = hid + (size_t)(base + s) * Hn;
      a0 += w * hp[t];
      a1 += w * hp[t + 256];
      a2 += w * hp[t + 512];
    }
  }
  out[obase + t] = a0;
  out[obase + 256 + t] = a1;
  out[obase + 512 + t] = a2;
}

// ---------------- launch
extern "C" void kernel_launch(void* const* d_in, const int* in_sizes, int n_in,
                              void* d_out, int out_size, void* d_ws, size_t ws_size,
                              hipStream_t stream) {
  const float* hidden = (const float*)d_in[0];
  const int* ids      = (const int*)d_in[1];
  const float* W      = (const float*)d_in[2];
  const float* bbias  = (const float*)d_in[3];
  const float* vvec   = (const float*)d_in[4];

  char* ws = (char*)d_ws;
  unsigned short* WBp  = (unsigned short*)(ws);            // 1,179,648 B
  float* scores        = (float*)(ws + 1179648);
  unsigned char* segv  = (unsigned char*)(ws + 1310720);
  int* nsep            = (int*)(ws + 1343488);

  convw_kernel<<<288, 256, 0, stream>>>(W, WBp);
  segscan_kernel<<<Bn, Sn, 0, stream>>>(ids, segv, nsep);
  score_gemm_kernel<<<BS / 64, 1024, 0, stream>>>(hidden, WBp, bbias, vvec, scores);
  pool_kernel<<<Bn * Mn, 256, 0, stream>>>(hidden, scores, segv, nsep, (float*)d_out);
}